// Round 2
// baseline (1238.386 us; speedup 1.0000x reference)
//
#include <hip/hip_runtime.h>
#include <cmath>

#define NN 50000

typedef short v8s __attribute__((ext_vector_type(8)));   // 8 x bf16 (4 VGPRs)
typedef float v4f __attribute__((ext_vector_type(4)));

__device__ __forceinline__ float b2f(unsigned short u) {
    return __uint_as_float(((unsigned int)u) << 16);
}
__device__ __forceinline__ unsigned short f2b(float f) {
    unsigned int x = __float_as_uint(f);
    x += 0x7fffu + ((x >> 16) & 1u);          // round-to-nearest-even
    return (unsigned short)(x >> 16);
}

// ---- dtype sniffer: mode=0 -> inputs are bf16, mode=1 -> inputs are float32 ----
// bf16 N(0,1): exponent field of every ushort is ~[100,140]. fp32: even ushorts are
// random low-mantissa bits (16% hit the range) -> count separates cleanly.
__global__ void sniff_kernel(const unsigned short* __restrict__ x, int* __restrict__ mode) {
    if (threadIdx.x == 0 && blockIdx.x == 0) {
        int c = 0;
        for (int i = 0; i < 128; ++i) {
            unsigned int e = (x[i] >> 7) & 0xFFu;
            if (e >= 100u && e <= 140u) ++c;
        }
        *mode = (c >= 112) ? 0 : 1;
    }
}

// ---- degree histogram ----
__global__ void deg_kernel(const int* __restrict__ dst, int* __restrict__ deg, int E) {
    int e = blockIdx.x * blockDim.x + threadIdx.x;
    if (e < E) atomicAdd(&deg[dst[e]], 1);
}

// ---- single-block exclusive scan: row_ptr, cursor, dinv ----
__global__ void scan_kernel(const int* __restrict__ deg, int* __restrict__ row_ptr,
                            int* __restrict__ cursor, float* __restrict__ dinv, int n) {
    __shared__ int sm[1024];
    __shared__ int carry;
    int t = threadIdx.x;
    if (t == 0) carry = 0;
    __syncthreads();
    for (int base = 0; base < n; base += 1024) {
        int i = base + t;
        int v = (i < n) ? deg[i] : 0;
        sm[t] = v;
        __syncthreads();
        for (int off = 1; off < 1024; off <<= 1) {
            int tmp = (t >= off) ? sm[t - off] : 0;
            __syncthreads();
            sm[t] += tmp;
            __syncthreads();
        }
        int incl = sm[t];
        int c = carry;
        __syncthreads();
        if (t == 1023) carry = c + incl;
        if (i < n) {
            int excl = c + incl - v;
            row_ptr[i] = excl;
            cursor[i]  = excl;
            dinv[i]    = (v > 0) ? rsqrtf((float)v) : 0.0f;
        }
        __syncthreads();
    }
    if (t == 0) row_ptr[n] = carry;
}

// ---- CSR fill (counting-sort placement) ----
__global__ void fill_kernel(const int* __restrict__ src, const int* __restrict__ dst,
                            int* __restrict__ cursor, int* __restrict__ csr, int E) {
    int e = blockIdx.x * blockDim.x + threadIdx.x;
    if (e < E) {
        int d = dst[e];
        int pos = atomicAdd(&cursor[d], 1);
        csr[pos] = src[e];
    }
}

// ---- W [K x F] (fp32 or bf16 per mode) -> WT [F x K] bf16 ----
__global__ void transpose_kernel(const void* __restrict__ W, unsigned short* __restrict__ WT,
                                 int K, int F, const int* __restrict__ modep) {
    int mode = *modep;
    int tid = blockIdx.x * blockDim.x + threadIdx.x;
    if (tid < K * F) {
        int n = tid / K, k = tid % K;
        unsigned short v = mode ? f2b(((const float*)W)[k * F + n])
                                : ((const unsigned short*)W)[k * F + n];
        WT[tid] = v;
    }
}

// ---- small convert (biases) ----
__global__ void cvt_kernel(const void* __restrict__ in, unsigned short* __restrict__ out,
                           int n, const int* __restrict__ modep) {
    int mode = *modep;
    int i = blockIdx.x * blockDim.x + threadIdx.x;
    if (i < n) out[i] = mode ? f2b(((const float*)in)[i]) : ((const unsigned short*)in)[i];
}

// ---- pack x (50000x128) into buf cols 0:128 (ld 512), converting if fp32 ----
__global__ void pack_kernel(const void* __restrict__ x, unsigned short* __restrict__ buf,
                            const int* __restrict__ modep) {
    int mode = *modep;
    int tid = blockIdx.x * blockDim.x + threadIdx.x;
    if (tid < NN * 128) {
        int n = tid >> 7, c = tid & 127;
        unsigned short v = mode ? f2b(((const float*)x)[tid]) : ((const unsigned short*)x)[tid];
        buf[n * 512 + c] = v;
    }
}

// ---- SpMM: one wave per dst node; x1[n] = -dinv[n] * sum_e dinv[src]*h[src] ----
template <int FPL>   // features per lane: F = 64*FPL (2 -> 128, 4 -> 256)
__global__ void spmm_kernel(const unsigned short* __restrict__ h, int ldh,
                            const int* __restrict__ row_ptr, const int* __restrict__ csr,
                            const float* __restrict__ dinv,
                            unsigned short* __restrict__ out, int ldo) {
    int node = blockIdx.x * 4 + (threadIdx.x >> 6);
    int lane = threadIdx.x & 63;
    int beg = row_ptr[node], end = row_ptr[node + 1];
    float acc[FPL];
#pragma unroll
    for (int i = 0; i < FPL; ++i) acc[i] = 0.f;
    const int col = lane * FPL;
    for (int j = beg; j < end; ++j) {
        int s = csr[j];
        float ds = dinv[s];
        const unsigned short* hp = h + (size_t)s * ldh + col;
        if (FPL == 4) {
            ushort4 v = *(const ushort4*)hp;
            acc[0] += ds * b2f(v.x); acc[1] += ds * b2f(v.y);
            acc[2] += ds * b2f(v.z); acc[3] += ds * b2f(v.w);
        } else {
            ushort2 v = *(const ushort2*)hp;
            acc[0] += ds * b2f(v.x); acc[1] += ds * b2f(v.y);
        }
    }
    float dn = -dinv[node];
    unsigned short* op = out + (size_t)node * ldo + col;
    if (FPL == 4) {
        ushort4 o;
        o.x = f2b(acc[0] * dn); o.y = f2b(acc[1] * dn);
        o.z = f2b(acc[2] * dn); o.w = f2b(acc[3] * dn);
        *(ushort4*)op = o;
    } else {
        ushort2 o;
        o.x = f2b(acc[0] * dn); o.y = f2b(acc[1] * dn);
        *(ushort2*)op = o;
    }
}

// ---- GEMM, in-place capable: out[M x NT*16] = A[M x K32*32 (ld lda)] @ W (+bias, opt tanh)
// 4 waves/block, wave -> 16 rows. Each wave preloads its FULL A rows into registers
// BEFORE any store (wave-ordered), so out may alias A's columns safely.
template <int K32, int NT>
__global__ void gemm_kernel(const unsigned short* __restrict__ A, int lda,
                            const unsigned short* __restrict__ WT,   // [NT*16 x K] bf16
                            const unsigned short* __restrict__ bias, // bf16
                            void* __restrict__ out, int ldo,
                            int M, int dotanh, int is_final, const int* __restrict__ modep) {
    constexpr int K = K32 * 32;
    int wave = threadIdx.x >> 6, lane = threadIdx.x & 63;
    int quad = lane >> 4, l16 = lane & 15;
    int m0 = blockIdx.x * 64 + wave * 16;
    int arow = m0 + l16;
    if (arow >= M) arow = M - 1;               // clamp (reads valid, writes guarded)
    const unsigned short* ap = A + (size_t)arow * lda + quad * 8;

    v8s af[K32];
#pragma unroll
    for (int j = 0; j < K32; ++j) af[j] = *(const v8s*)(ap + j * 32);

    int fin = is_final ? *modep : 0;           // final layer writes fp32 iff inputs were fp32

#pragma unroll
    for (int i = 0; i < NT; ++i) {
        v4f acc = (v4f){0.f, 0.f, 0.f, 0.f};
#pragma unroll
        for (int j = 0; j < K32; ++j) {
            const unsigned short* bp = WT + (size_t)(i * 16 + l16) * K + j * 32 + quad * 8;
            v8s bf = *(const v8s*)bp;
            acc = __builtin_amdgcn_mfma_f32_16x16x32_bf16(af[j], bf, acc, 0, 0, 0);
        }
        int colc = i * 16 + l16;
        float bv = b2f(bias[colc]);
#pragma unroll
        for (int r = 0; r < 4; ++r) {
            int row = m0 + quad * 4 + r;
            if (row < M) {
                float v = acc[r] + bv;
                if (dotanh) v = tanhf(v);
                if (fin) ((float*)out)[(size_t)row * ldo + colc] = v;
                else     ((unsigned short*)out)[(size_t)row * ldo + colc] = f2b(v);
            }
        }
    }
}

static inline size_t al256(size_t x) { return (x + 255) & ~(size_t)255; }

extern "C" void kernel_launch(void* const* d_in, const int* in_sizes, int n_in,
                              void* d_out, int out_size, void* d_ws, size_t ws_size,
                              hipStream_t stream) {
    const void* x  = d_in[0];
    const int* src = (const int*)d_in[1];
    const int* dst = (const int*)d_in[2];
    const void* W1 = d_in[3]; const void* b1 = d_in[4];
    const void* W2 = d_in[5]; const void* b2 = d_in[6];
    const void* W3 = d_in[7]; const void* b3 = d_in[8];
    const int E = in_sizes[1];

    // workspace carve-up (~55.8 MB)
    char* p = (char*)d_ws;
    int* mode     = (int*)p;            p += 256;
    int* deg      = (int*)p;            p += al256((size_t)NN * 4);
    int* row_ptr  = (int*)p;            p += al256((size_t)(NN + 1) * 4);
    int* cursor   = (int*)p;            p += al256((size_t)NN * 4);
    float* dinv   = (float*)p;          p += al256((size_t)NN * 4);
    int* csr      = (int*)p;            p += al256((size_t)E * 4);
    unsigned short* WT1 = (unsigned short*)p; p += al256((size_t)256 * 256 * 2);
    unsigned short* WT2 = (unsigned short*)p; p += al256((size_t)256 * 512 * 2);
    unsigned short* WT3 = (unsigned short*)p; p += al256((size_t)128 * 512 * 2);
    unsigned short* bb1 = (unsigned short*)p; p += al256((size_t)256 * 2);
    unsigned short* bb2 = (unsigned short*)p; p += al256((size_t)256 * 2);
    unsigned short* bb3 = (unsigned short*)p; p += al256((size_t)128 * 2);
    unsigned short* buf = (unsigned short*)p; p += al256((size_t)NN * 512 * 2);

    hipMemsetAsync(deg, 0, (size_t)NN * 4, stream);
    sniff_kernel<<<1, 64, 0, stream>>>((const unsigned short*)x, mode);

    int eb = (E + 255) / 256;
    deg_kernel<<<eb, 256, 0, stream>>>(dst, deg, E);
    scan_kernel<<<1, 1024, 0, stream>>>(deg, row_ptr, cursor, dinv, NN);
    fill_kernel<<<eb, 256, 0, stream>>>(src, dst, cursor, csr, E);

    transpose_kernel<<<(256 * 256 + 255) / 256, 256, 0, stream>>>(W1, WT1, 256, 256, mode);
    transpose_kernel<<<(512 * 256 + 255) / 256, 256, 0, stream>>>(W2, WT2, 512, 256, mode);
    transpose_kernel<<<(512 * 128 + 255) / 256, 256, 0, stream>>>(W3, WT3, 512, 128, mode);
    cvt_kernel<<<1, 256, 0, stream>>>(b1, bb1, 256, mode);
    cvt_kernel<<<1, 256, 0, stream>>>(b2, bb2, 256, mode);
    cvt_kernel<<<1, 256, 0, stream>>>(b3, bb3, 128, mode);
    pack_kernel<<<(NN * 128 + 255) / 256, 256, 0, stream>>>(x, buf, mode);

    const int SPMM_GRID = NN / 4;          // 4 waves (nodes) per 256-thread block
    const int GB = (NN + 63) / 64;         // gemm blocks (rows)

    // L1: buf = [x(0:128) | x1(128:256)]; gemm K=256 in-place -> cols 0:256
    spmm_kernel<2><<<SPMM_GRID, 256, 0, stream>>>(buf, 512, row_ptr, csr, dinv, buf + 128, 512);
    gemm_kernel<8, 16><<<GB, 256, 0, stream>>>(buf, 512, WT1, bb1, buf, 512, NN, 1, 0, mode);
    // L2..L4: x1 into cols 256:512, gemm K=512 in-place -> cols 0:256
    spmm_kernel<4><<<SPMM_GRID, 256, 0, stream>>>(buf, 512, row_ptr, csr, dinv, buf + 256, 512);
    gemm_kernel<16, 16><<<GB, 256, 0, stream>>>(buf, 512, WT2, bb2, buf, 512, NN, 1, 0, mode);
    spmm_kernel<4><<<SPMM_GRID, 256, 0, stream>>>(buf, 512, row_ptr, csr, dinv, buf + 256, 512);
    gemm_kernel<16, 16><<<GB, 256, 0, stream>>>(buf, 512, WT2, bb2, buf, 512, NN, 1, 0, mode);
    spmm_kernel<4><<<SPMM_GRID, 256, 0, stream>>>(buf, 512, row_ptr, csr, dinv, buf + 256, 512);
    gemm_kernel<16, 16><<<GB, 256, 0, stream>>>(buf, 512, WT2, bb2, buf, 512, NN, 1, 0, mode);
    // L5 (no tanh) -> d_out (50000 x 128, bf16 or fp32 per mode)
    spmm_kernel<4><<<SPMM_GRID, 256, 0, stream>>>(buf, 512, row_ptr, csr, dinv, buf + 256, 512);
    gemm_kernel<16, 8><<<GB, 256, 0, stream>>>(buf, 512, WT3, bb3, d_out, 128, NN, 0, 1, mode);
}

// Round 3
// 995.639 us; speedup vs baseline: 1.2438x; 1.2438x over previous
//
#include <hip/hip_runtime.h>
#include <cmath>

#define NN 50000

typedef short v8s __attribute__((ext_vector_type(8)));   // 8 x bf16 (4 VGPRs)
typedef float v4f __attribute__((ext_vector_type(4)));

__device__ __forceinline__ float b2f(unsigned short u) {
    return __uint_as_float(((unsigned int)u) << 16);
}
__device__ __forceinline__ unsigned short f2b(float f) {
    unsigned int x = __float_as_uint(f);
    x += 0x7fffu + ((x >> 16) & 1u);          // round-to-nearest-even
    return (unsigned short)(x >> 16);
}

// async global->LDS, 16B per lane. LDS dest must be wave-contiguous (base + lane*16).
__device__ __forceinline__ void gld16(const void* g, void* l) {
    __builtin_amdgcn_global_load_lds(
        (const __attribute__((address_space(1))) unsigned int*)g,
        (__attribute__((address_space(3))) unsigned int*)l, 16, 0, 0);
}

// ---- dtype sniffer: mode=0 -> inputs are bf16, mode=1 -> inputs are float32 ----
__global__ void sniff_kernel(const unsigned short* __restrict__ x, int* __restrict__ mode) {
    if (threadIdx.x == 0 && blockIdx.x == 0) {
        int c = 0;
        for (int i = 0; i < 128; ++i) {
            unsigned int e = (x[i] >> 7) & 0xFFu;
            if (e >= 100u && e <= 140u) ++c;
        }
        *mode = (c >= 112) ? 0 : 1;
    }
}

// ---- degree histogram ----
__global__ void deg_kernel(const int* __restrict__ dst, int* __restrict__ deg, int E) {
    int e = blockIdx.x * blockDim.x + threadIdx.x;
    if (e < E) atomicAdd(&deg[dst[e]], 1);
}

// ---- single-block scan: chunk-local sums -> 1024-wide scan -> chunk writeback ----
__global__ void scan_kernel(const int* __restrict__ deg, int* __restrict__ row_ptr,
                            int* __restrict__ cursor, float* __restrict__ dinv, int n) {
    __shared__ int sm[1024];
    int t = threadIdx.x;
    const int CH = (n + 1023) / 1024;
    int base = t * CH;
    int s = 0;
    for (int i = 0; i < CH; ++i) {
        int idx = base + i;
        if (idx < n) s += deg[idx];
    }
    sm[t] = s;
    __syncthreads();
    for (int off = 1; off < 1024; off <<= 1) {
        int v = (t >= off) ? sm[t - off] : 0;
        __syncthreads();
        sm[t] += v;
        __syncthreads();
    }
    int run = sm[t] - s;               // exclusive prefix of this chunk
    for (int i = 0; i < CH; ++i) {
        int idx = base + i;
        if (idx < n) {
            int v = deg[idx];
            row_ptr[idx] = run;
            cursor[idx]  = run;
            dinv[idx]    = (v > 0) ? rsqrtf((float)v) : 0.0f;
            run += v;
        }
    }
    if (t == 1023) row_ptr[n] = sm[1023];
}

// ---- CSR fill (counting-sort placement) ----
__global__ void fill_kernel(const int* __restrict__ src, const int* __restrict__ dst,
                            int* __restrict__ cursor, int* __restrict__ csr, int E) {
    int e = blockIdx.x * blockDim.x + threadIdx.x;
    if (e < E) {
        int d = dst[e];
        int pos = atomicAdd(&cursor[d], 1);
        csr[pos] = src[e];
    }
}

// ---- W [K x F] (fp32 or bf16 per mode) -> WT [F x K] bf16 ----
__global__ void transpose_kernel(const void* __restrict__ W, unsigned short* __restrict__ WT,
                                 int K, int F, const int* __restrict__ modep) {
    int mode = *modep;
    int tid = blockIdx.x * blockDim.x + threadIdx.x;
    if (tid < K * F) {
        int n = tid / K, k = tid % K;
        unsigned short v = mode ? f2b(((const float*)W)[k * F + n])
                                : ((const unsigned short*)W)[k * F + n];
        WT[tid] = v;
    }
}

// ---- small convert (biases) ----
__global__ void cvt_kernel(const void* __restrict__ in, unsigned short* __restrict__ out,
                           int n, const int* __restrict__ modep) {
    int mode = *modep;
    int i = blockIdx.x * blockDim.x + threadIdx.x;
    if (i < n) out[i] = mode ? f2b(((const float*)in)[i]) : ((const unsigned short*)in)[i];
}

// ---- pack x (50000x128) into buf cols 0:128 (ld 512), 16B chunks ----
__global__ void pack_kernel(const void* __restrict__ x, unsigned short* __restrict__ buf,
                            const int* __restrict__ modep) {
    int mode = *modep;
    int tid = blockIdx.x * blockDim.x + threadIdx.x;
    if (tid < NN * 16) {                       // 16 chunks of 8 bf16 per row
        int n = tid >> 4, c = tid & 15;
        if (mode == 0) {
            ((uint4*)buf)[n * 64 + c] = ((const uint4*)x)[n * 16 + c];
        } else {
            const float* xf = (const float*)x + (size_t)n * 128 + c * 8;
            unsigned short o[8];
#pragma unroll
            for (int i = 0; i < 8; ++i) o[i] = f2b(xf[i]);
            *(uint4*)&buf[(size_t)n * 512 + c * 8] = *(const uint4*)o;
        }
    }
}

// ---- SpMM: one wave per dst node; x1[n] = -dinv[n] * sum_e dinv[src]*h[src] ----
template <int FPL>   // features per lane: F = 64*FPL (2 -> 128, 4 -> 256)
__global__ void spmm_kernel(const unsigned short* __restrict__ h, int ldh,
                            const int* __restrict__ row_ptr, const int* __restrict__ csr,
                            const float* __restrict__ dinv,
                            unsigned short* __restrict__ out, int ldo) {
    int node = blockIdx.x * 4 + (threadIdx.x >> 6);
    int lane = threadIdx.x & 63;
    int beg = row_ptr[node], end = row_ptr[node + 1];
    float acc[FPL];
#pragma unroll
    for (int i = 0; i < FPL; ++i) acc[i] = 0.f;
    const int col = lane * FPL;
    for (int j = beg; j < end; ++j) {
        int s = csr[j];
        float ds = dinv[s];
        const unsigned short* hp = h + (size_t)s * ldh + col;
        if (FPL == 4) {
            ushort4 v = *(const ushort4*)hp;
            acc[0] += ds * b2f(v.x); acc[1] += ds * b2f(v.y);
            acc[2] += ds * b2f(v.z); acc[3] += ds * b2f(v.w);
        } else {
            ushort2 v = *(const ushort2*)hp;
            acc[0] += ds * b2f(v.x); acc[1] += ds * b2f(v.y);
        }
    }
    float dn = -dinv[node];
    unsigned short* op = out + (size_t)node * ldo + col;
    if (FPL == 4) {
        ushort4 o;
        o.x = f2b(acc[0] * dn); o.y = f2b(acc[1] * dn);
        o.z = f2b(acc[2] * dn); o.w = f2b(acc[3] * dn);
        *(ushort4*)op = o;
    } else {
        ushort2 o;
        o.x = f2b(acc[0] * dn); o.y = f2b(acc[1] * dn);
        *(ushort2*)op = o;
    }
}

// ---- LDS-staged MFMA GEMM (m97 structure) ----
// Block: 256 thr = 4 waves. Tile: 64(M) x NB(N), NB = 4*NTPW*16 (full output width).
// Wave w covers all 64 rows x cols [w*NTPW*16, +NTPW*16). K-loop BK=32, A/B tiles
// staged via global_load_lds(16B). In-place safe: block owns its rows, all A reads
// (K-loop) complete before epilogue stores.
template <int K32, int NTPW>
__global__ void gemm_lds_kernel(const unsigned short* __restrict__ A, int lda,
                                const unsigned short* __restrict__ WT,   // [NB x K] bf16
                                const unsigned short* __restrict__ bias, // bf16
                                void* __restrict__ out, int ldo,
                                int M, int dotanh, int is_final, const int* __restrict__ modep) {
    constexpr int K  = K32 * 32;
    constexpr int NB = 4 * NTPW * 16;
    constexpr int ACHUNK = 64 * 32 * 2 / 16;          // 256 16B-chunks
    constexpr int BCHUNK = NB * 32 * 2 / 16;
    constexpr int ROUNDS = (ACHUNK + BCHUNK) / 256;
    __shared__ unsigned short lds[(64 + NB) * 32];    // A[64][32] then B[NB][32]

    const int tid = threadIdx.x;
    const int wave = tid >> 6, lane = tid & 63, quad = lane >> 4, l16 = lane & 15;
    const int m0 = blockIdx.x * 64;

    v4f acc[4][NTPW];
#pragma unroll
    for (int mi = 0; mi < 4; ++mi)
#pragma unroll
        for (int ni = 0; ni < NTPW; ++ni) acc[mi][ni] = (v4f){0.f, 0.f, 0.f, 0.f};

    // precompute per-round global base pointers (k0-invariant part)
    const unsigned short* gp[ROUNDS];
#pragma unroll
    for (int r = 0; r < ROUNDS; ++r) {
        int c = tid + r * 256;
        if (c < ACHUNK) {
            int row = m0 + (c >> 2);
            if (row >= M) row = M - 1;
            gp[r] = A + (size_t)row * lda + (c & 3) * 8;
        } else {
            int cb = c - ACHUNK;
            gp[r] = WT + (size_t)(cb >> 2) * K + (cb & 3) * 8;
        }
    }

    const unsigned short* aT = lds;
    const unsigned short* bT = lds + 64 * 32;

    for (int k0 = 0; k0 < K; k0 += 32) {
#pragma unroll
        for (int r = 0; r < ROUNDS; ++r) {
            int c = tid + r * 256;
            gld16(gp[r] + k0, (void*)&lds[c * 8]);
        }
        __syncthreads();

        v8s a_frag[4], b_frag[NTPW];
#pragma unroll
        for (int mi = 0; mi < 4; ++mi)
            a_frag[mi] = *(const v8s*)&aT[(mi * 16 + l16) * 32 + quad * 8];
#pragma unroll
        for (int ni = 0; ni < NTPW; ++ni)
            b_frag[ni] = *(const v8s*)&bT[(wave * NTPW * 16 + ni * 16 + l16) * 32 + quad * 8];
#pragma unroll
        for (int mi = 0; mi < 4; ++mi)
#pragma unroll
            for (int ni = 0; ni < NTPW; ++ni)
                acc[mi][ni] = __builtin_amdgcn_mfma_f32_16x16x32_bf16(a_frag[mi], b_frag[ni],
                                                                      acc[mi][ni], 0, 0, 0);
        __syncthreads();
    }

    int fin = is_final ? *modep : 0;
#pragma unroll
    for (int ni = 0; ni < NTPW; ++ni) {
        int colc = wave * NTPW * 16 + ni * 16 + l16;
        float bv = b2f(bias[colc]);
#pragma unroll
        for (int mi = 0; mi < 4; ++mi) {
#pragma unroll
            for (int r = 0; r < 4; ++r) {
                int row = m0 + mi * 16 + quad * 4 + r;
                if (row < M) {
                    float v = acc[mi][ni][r] + bv;
                    if (dotanh) v = tanhf(v);
                    if (fin) ((float*)out)[(size_t)row * ldo + colc] = v;
                    else     ((unsigned short*)out)[(size_t)row * ldo + colc] = f2b(v);
                }
            }
        }
    }
}

static inline size_t al256(size_t x) { return (x + 255) & ~(size_t)255; }

extern "C" void kernel_launch(void* const* d_in, const int* in_sizes, int n_in,
                              void* d_out, int out_size, void* d_ws, size_t ws_size,
                              hipStream_t stream) {
    const void* x  = d_in[0];
    const int* src = (const int*)d_in[1];
    const int* dst = (const int*)d_in[2];
    const void* W1 = d_in[3]; const void* b1 = d_in[4];
    const void* W2 = d_in[5]; const void* b2 = d_in[6];
    const void* W3 = d_in[7]; const void* b3 = d_in[8];
    const int E = in_sizes[1];

    // workspace carve-up (~55.8 MB)
    char* p = (char*)d_ws;
    int* mode     = (int*)p;            p += 256;
    int* deg      = (int*)p;            p += al256((size_t)NN * 4);
    int* row_ptr  = (int*)p;            p += al256((size_t)(NN + 1) * 4);
    int* cursor   = (int*)p;            p += al256((size_t)NN * 4);
    float* dinv   = (float*)p;          p += al256((size_t)NN * 4);
    int* csr      = (int*)p;            p += al256((size_t)E * 4);
    unsigned short* WT1 = (unsigned short*)p; p += al256((size_t)256 * 256 * 2);
    unsigned short* WT2 = (unsigned short*)p; p += al256((size_t)256 * 512 * 2);
    unsigned short* WT3 = (unsigned short*)p; p += al256((size_t)128 * 512 * 2);
    unsigned short* bb1 = (unsigned short*)p; p += al256((size_t)256 * 2);
    unsigned short* bb2 = (unsigned short*)p; p += al256((size_t)256 * 2);
    unsigned short* bb3 = (unsigned short*)p; p += al256((size_t)128 * 2);
    unsigned short* buf = (unsigned short*)p; p += al256((size_t)NN * 512 * 2);

    hipMemsetAsync(deg, 0, (size_t)NN * 4, stream);
    sniff_kernel<<<1, 64, 0, stream>>>((const unsigned short*)x, mode);

    int eb = (E + 255) / 256;
    deg_kernel<<<eb, 256, 0, stream>>>(dst, deg, E);
    scan_kernel<<<1, 1024, 0, stream>>>(deg, row_ptr, cursor, dinv, NN);
    fill_kernel<<<eb, 256, 0, stream>>>(src, dst, cursor, csr, E);

    transpose_kernel<<<(256 * 256 + 255) / 256, 256, 0, stream>>>(W1, WT1, 256, 256, mode);
    transpose_kernel<<<(512 * 256 + 255) / 256, 256, 0, stream>>>(W2, WT2, 512, 256, mode);
    transpose_kernel<<<(512 * 128 + 255) / 256, 256, 0, stream>>>(W3, WT3, 512, 128, mode);
    cvt_kernel<<<1, 256, 0, stream>>>(b1, bb1, 256, mode);
    cvt_kernel<<<1, 256, 0, stream>>>(b2, bb2, 256, mode);
    cvt_kernel<<<1, 256, 0, stream>>>(b3, bb3, 128, mode);
    pack_kernel<<<(NN * 16 + 255) / 256, 256, 0, stream>>>(x, buf, mode);

    const int SPMM_GRID = NN / 4;          // 4 waves (nodes) per 256-thread block
    const int GB = (NN + 63) / 64;         // gemm blocks (rows)

    // L1: buf = [x(0:128) | x1(128:256)]; gemm K=256 in-place -> cols 0:256
    spmm_kernel<2><<<SPMM_GRID, 256, 0, stream>>>(buf, 512, row_ptr, csr, dinv, buf + 128, 512);
    gemm_lds_kernel<8, 4><<<GB, 256, 0, stream>>>(buf, 512, WT1, bb1, buf, 512, NN, 1, 0, mode);
    // L2..L4: x1 into cols 256:512, gemm K=512 in-place -> cols 0:256
    spmm_kernel<4><<<SPMM_GRID, 256, 0, stream>>>(buf, 512, row_ptr, csr, dinv, buf + 256, 512);
    gemm_lds_kernel<16, 4><<<GB, 256, 0, stream>>>(buf, 512, WT2, bb2, buf, 512, NN, 1, 0, mode);
    spmm_kernel<4><<<SPMM_GRID, 256, 0, stream>>>(buf, 512, row_ptr, csr, dinv, buf + 256, 512);
    gemm_lds_kernel<16, 4><<<GB, 256, 0, stream>>>(buf, 512, WT2, bb2, buf, 512, NN, 1, 0, mode);
    spmm_kernel<4><<<SPMM_GRID, 256, 0, stream>>>(buf, 512, row_ptr, csr, dinv, buf + 256, 512);
    gemm_lds_kernel<16, 4><<<GB, 256, 0, stream>>>(buf, 512, WT2, bb2, buf, 512, NN, 1, 0, mode);
    // L5 (no tanh) -> d_out (50000 x 128, bf16 or fp32 per mode)
    spmm_kernel<4><<<SPMM_GRID, 256, 0, stream>>>(buf, 512, row_ptr, csr, dinv, buf + 256, 512);
    gemm_lds_kernel<16, 2><<<GB, 256, 0, stream>>>(buf, 512, WT3, bb3, d_out, 128, NN, 0, 1, mode);
}

// Round 4
// 637.691 us; speedup vs baseline: 1.9420x; 1.5613x over previous
//
#include <hip/hip_runtime.h>
#include <cmath>

#define NN 50000

typedef short v8s __attribute__((ext_vector_type(8)));   // 8 x bf16 (4 VGPRs)
typedef float v4f __attribute__((ext_vector_type(4)));

__device__ __forceinline__ float b2f(unsigned short u) {
    return __uint_as_float(((unsigned int)u) << 16);
}
__device__ __forceinline__ unsigned short f2b(float f) {
    unsigned int x = __float_as_uint(f);
    x += 0x7fffu + ((x >> 16) & 1u);          // round-to-nearest-even
    return (unsigned short)(x >> 16);
}

// async global->LDS, 16B per lane. LDS dest must be wave-contiguous (base + lane*16).
__device__ __forceinline__ void gld16(const void* g, void* l) {
    __builtin_amdgcn_global_load_lds(
        (const __attribute__((address_space(1))) unsigned int*)g,
        (__attribute__((address_space(3))) unsigned int*)l, 16, 0, 0);
}

// ---- dtype sniffer: mode=0 -> inputs are bf16, mode=1 -> inputs are float32 ----
__global__ void sniff_kernel(const unsigned short* __restrict__ x, int* __restrict__ mode) {
    if (threadIdx.x == 0 && blockIdx.x == 0) {
        int c = 0;
        for (int i = 0; i < 128; ++i) {
            unsigned int e = (x[i] >> 7) & 0xFFu;
            if (e >= 100u && e <= 140u) ++c;
        }
        *mode = (c >= 112) ? 0 : 1;
    }
}

// ---- degree histogram ----
__global__ void deg_kernel(const int* __restrict__ dst, int* __restrict__ deg, int E) {
    int e = blockIdx.x * blockDim.x + threadIdx.x;
    if (e < E) atomicAdd(&deg[dst[e]], 1);
}

// ---- hierarchical scan, stage 1: per-block (1024 elems) partial sums ----
__global__ void part_kernel(const int* __restrict__ deg, int* __restrict__ part, int n) {
    __shared__ int sm[256];
    int t = threadIdx.x;
    int base = blockIdx.x * 1024 + t * 4;
    int s = 0;
    if (base + 3 < n) {
        int4 v = *(const int4*)(deg + base);
        s = v.x + v.y + v.z + v.w;
    } else {
        for (int i = 0; i < 4; ++i) if (base + i < n) s += deg[base + i];
    }
    sm[t] = s;
    __syncthreads();
    for (int off = 128; off > 0; off >>= 1) {
        if (t < off) sm[t] += sm[t + off];
        __syncthreads();
    }
    if (t == 0) part[blockIdx.x] = sm[0];
}

// ---- stage 2: one wave exclusive-scans the partials (nb <= 64) ----
__global__ void partscan_kernel(int* __restrict__ part, int nb, int* __restrict__ total_out) {
    int t = threadIdx.x;
    int orig = (t < nb) ? part[t] : 0;
    int v = orig;
    for (int off = 1; off < 64; off <<= 1) {
        int u = __shfl_up(v, off, 64);
        if (t >= off) v += u;
    }
    if (t < nb) part[t] = v - orig;       // exclusive
    if (t == 63) *total_out = v;          // total = E
}

// ---- stage 3: block-local scan + offset; write row_ptr/cursor/dinv ----
__global__ void scan2_kernel(const int* __restrict__ deg, const int* __restrict__ part,
                             int* __restrict__ row_ptr, int* __restrict__ cursor,
                             float* __restrict__ dinv, int n) {
    __shared__ int sm[256];
    int t = threadIdx.x;
    int base = blockIdx.x * 1024 + t * 4;
    int d[4]; int s = 0;
#pragma unroll
    for (int i = 0; i < 4; ++i) { d[i] = (base + i < n) ? deg[base + i] : 0; s += d[i]; }
    sm[t] = s;
    __syncthreads();
    for (int off = 1; off < 256; off <<= 1) {
        int u = (t >= off) ? sm[t - off] : 0;
        __syncthreads();
        sm[t] += u;
        __syncthreads();
    }
    int run = part[blockIdx.x] + sm[t] - s;   // exclusive prefix at base
#pragma unroll
    for (int i = 0; i < 4; ++i) {
        int idx = base + i;
        if (idx < n) {
            row_ptr[idx] = run;
            cursor[idx]  = run;
            dinv[idx]    = (d[i] > 0) ? rsqrtf((float)d[i]) : 0.0f;
            run += d[i];
        }
    }
}

// ---- CSR fill (counting-sort placement) ----
__global__ void fill_kernel(const int* __restrict__ src, const int* __restrict__ dst,
                            int* __restrict__ cursor, int* __restrict__ csr, int E) {
    int e = blockIdx.x * blockDim.x + threadIdx.x;
    if (e < E) {
        int d = dst[e];
        int pos = atomicAdd(&cursor[d], 1);
        csr[pos] = src[e];
    }
}

// ---- W [K x F] (fp32 or bf16 per mode) -> WT [F x K] bf16 ----
__global__ void transpose_kernel(const void* __restrict__ W, unsigned short* __restrict__ WT,
                                 int K, int F, const int* __restrict__ modep) {
    int mode = *modep;
    int tid = blockIdx.x * blockDim.x + threadIdx.x;
    if (tid < K * F) {
        int n = tid / K, k = tid % K;
        unsigned short v = mode ? f2b(((const float*)W)[k * F + n])
                                : ((const unsigned short*)W)[k * F + n];
        WT[tid] = v;
    }
}

// ---- small convert (biases) ----
__global__ void cvt_kernel(const void* __restrict__ in, unsigned short* __restrict__ out,
                           int n, const int* __restrict__ modep) {
    int mode = *modep;
    int i = blockIdx.x * blockDim.x + threadIdx.x;
    if (i < n) out[i] = mode ? f2b(((const float*)in)[i]) : ((const unsigned short*)in)[i];
}

// ---- pack x (50000x128) into buf cols 0:128 (ld 512), 16B chunks ----
__global__ void pack_kernel(const void* __restrict__ x, unsigned short* __restrict__ buf,
                            const int* __restrict__ modep) {
    int mode = *modep;
    int tid = blockIdx.x * blockDim.x + threadIdx.x;
    if (tid < NN * 16) {                       // 16 chunks of 8 bf16 per row
        int n = tid >> 4, c = tid & 15;
        if (mode == 0) {
            ((uint4*)buf)[n * 64 + c] = ((const uint4*)x)[n * 16 + c];
        } else {
            const float* xf = (const float*)x + (size_t)n * 128 + c * 8;
            unsigned short o[8];
#pragma unroll
            for (int i = 0; i < 8; ++i) o[i] = f2b(xf[i]);
            *(uint4*)&buf[(size_t)n * 512 + c * 8] = *(const uint4*)o;
        }
    }
}

// ---- SpMM: one wave per dst node; x1[n] = -dinv[n] * sum_e dinv[src]*h[src]
// Edge loop unrolled x4: 4 independent index/dinv/row loads in flight per iter.
template <int FPL>   // features per lane: F = 64*FPL (2 -> 128, 4 -> 256)
__global__ void spmm_kernel(const unsigned short* __restrict__ h, int ldh,
                            const int* __restrict__ row_ptr, const int* __restrict__ csr,
                            const float* __restrict__ dinv,
                            unsigned short* __restrict__ out, int ldo) {
    int node = blockIdx.x * 4 + (threadIdx.x >> 6);
    int lane = threadIdx.x & 63;
    int beg = row_ptr[node], end = row_ptr[node + 1];
    float acc[FPL];
#pragma unroll
    for (int i = 0; i < FPL; ++i) acc[i] = 0.f;
    const int col = lane * FPL;

    int j = beg;
    for (; j + 3 < end; j += 4) {
        int s0 = csr[j], s1 = csr[j + 1], s2 = csr[j + 2], s3 = csr[j + 3];
        float d0 = dinv[s0], d1 = dinv[s1], d2 = dinv[s2], d3 = dinv[s3];
        if (FPL == 4) {
            ushort4 v0 = *(const ushort4*)(h + (size_t)s0 * ldh + col);
            ushort4 v1 = *(const ushort4*)(h + (size_t)s1 * ldh + col);
            ushort4 v2 = *(const ushort4*)(h + (size_t)s2 * ldh + col);
            ushort4 v3 = *(const ushort4*)(h + (size_t)s3 * ldh + col);
            acc[0] += d0 * b2f(v0.x) + d1 * b2f(v1.x) + d2 * b2f(v2.x) + d3 * b2f(v3.x);
            acc[1] += d0 * b2f(v0.y) + d1 * b2f(v1.y) + d2 * b2f(v2.y) + d3 * b2f(v3.y);
            acc[2] += d0 * b2f(v0.z) + d1 * b2f(v1.z) + d2 * b2f(v2.z) + d3 * b2f(v3.z);
            acc[3] += d0 * b2f(v0.w) + d1 * b2f(v1.w) + d2 * b2f(v2.w) + d3 * b2f(v3.w);
        } else {
            ushort2 v0 = *(const ushort2*)(h + (size_t)s0 * ldh + col);
            ushort2 v1 = *(const ushort2*)(h + (size_t)s1 * ldh + col);
            ushort2 v2 = *(const ushort2*)(h + (size_t)s2 * ldh + col);
            ushort2 v3 = *(const ushort2*)(h + (size_t)s3 * ldh + col);
            acc[0] += d0 * b2f(v0.x) + d1 * b2f(v1.x) + d2 * b2f(v2.x) + d3 * b2f(v3.x);
            acc[1] += d0 * b2f(v0.y) + d1 * b2f(v1.y) + d2 * b2f(v2.y) + d3 * b2f(v3.y);
        }
    }
    for (; j < end; ++j) {
        int s = csr[j];
        float ds = dinv[s];
        const unsigned short* hp = h + (size_t)s * ldh + col;
        if (FPL == 4) {
            ushort4 v = *(const ushort4*)hp;
            acc[0] += ds * b2f(v.x); acc[1] += ds * b2f(v.y);
            acc[2] += ds * b2f(v.z); acc[3] += ds * b2f(v.w);
        } else {
            ushort2 v = *(const ushort2*)hp;
            acc[0] += ds * b2f(v.x); acc[1] += ds * b2f(v.y);
        }
    }

    float dn = -dinv[node];
    unsigned short* op = out + (size_t)node * ldo + col;
    if (FPL == 4) {
        ushort4 o;
        o.x = f2b(acc[0] * dn); o.y = f2b(acc[1] * dn);
        o.z = f2b(acc[2] * dn); o.w = f2b(acc[3] * dn);
        *(ushort4*)op = o;
    } else {
        ushort2 o;
        o.x = f2b(acc[0] * dn); o.y = f2b(acc[1] * dn);
        *(ushort2*)op = o;
    }
}

// ---- LDS-staged MFMA GEMM (m97 structure) ----
// Block: 256 thr = 4 waves. Tile: 64(M) x NB(N), NB = 4*NTPW*16 (full output width).
// Wave w covers all 64 rows x cols [w*NTPW*16, +NTPW*16). K-loop BK=32, A/B tiles
// staged via global_load_lds(16B). In-place safe: block owns its rows, all A reads
// (K-loop) complete before epilogue stores.
template <int K32, int NTPW>
__global__ void gemm_lds_kernel(const unsigned short* __restrict__ A, int lda,
                                const unsigned short* __restrict__ WT,   // [NB x K] bf16
                                const unsigned short* __restrict__ bias, // bf16
                                void* __restrict__ out, int ldo,
                                int M, int dotanh, int is_final, const int* __restrict__ modep) {
    constexpr int K  = K32 * 32;
    constexpr int NB = 4 * NTPW * 16;
    constexpr int ACHUNK = 64 * 32 * 2 / 16;          // 256 16B-chunks
    constexpr int BCHUNK = NB * 32 * 2 / 16;
    constexpr int ROUNDS = (ACHUNK + BCHUNK) / 256;
    __shared__ unsigned short lds[(64 + NB) * 32];    // A[64][32] then B[NB][32]

    const int tid = threadIdx.x;
    const int wave = tid >> 6, lane = tid & 63, quad = lane >> 4, l16 = lane & 15;
    const int m0 = blockIdx.x * 64;

    v4f acc[4][NTPW];
#pragma unroll
    for (int mi = 0; mi < 4; ++mi)
#pragma unroll
        for (int ni = 0; ni < NTPW; ++ni) acc[mi][ni] = (v4f){0.f, 0.f, 0.f, 0.f};

    // precompute per-round global base pointers (k0-invariant part)
    const unsigned short* gp[ROUNDS];
#pragma unroll
    for (int r = 0; r < ROUNDS; ++r) {
        int c = tid + r * 256;
        if (c < ACHUNK) {
            int row = m0 + (c >> 2);
            if (row >= M) row = M - 1;
            gp[r] = A + (size_t)row * lda + (c & 3) * 8;
        } else {
            int cb = c - ACHUNK;
            gp[r] = WT + (size_t)(cb >> 2) * K + (cb & 3) * 8;
        }
    }

    const unsigned short* aT = lds;
    const unsigned short* bT = lds + 64 * 32;

    for (int k0 = 0; k0 < K; k0 += 32) {
#pragma unroll
        for (int r = 0; r < ROUNDS; ++r) {
            int c = tid + r * 256;
            gld16(gp[r] + k0, (void*)&lds[c * 8]);
        }
        __syncthreads();

        v8s a_frag[4], b_frag[NTPW];
#pragma unroll
        for (int mi = 0; mi < 4; ++mi)
            a_frag[mi] = *(const v8s*)&aT[(mi * 16 + l16) * 32 + quad * 8];
#pragma unroll
        for (int ni = 0; ni < NTPW; ++ni)
            b_frag[ni] = *(const v8s*)&bT[(wave * NTPW * 16 + ni * 16 + l16) * 32 + quad * 8];
#pragma unroll
        for (int mi = 0; mi < 4; ++mi)
#pragma unroll
            for (int ni = 0; ni < NTPW; ++ni)
                acc[mi][ni] = __builtin_amdgcn_mfma_f32_16x16x32_bf16(a_frag[mi], b_frag[ni],
                                                                      acc[mi][ni], 0, 0, 0);
        __syncthreads();
    }

    int fin = is_final ? *modep : 0;
#pragma unroll
    for (int ni = 0; ni < NTPW; ++ni) {
        int colc = wave * NTPW * 16 + ni * 16 + l16;
        float bv = b2f(bias[colc]);
#pragma unroll
        for (int mi = 0; mi < 4; ++mi) {
#pragma unroll
            for (int r = 0; r < 4; ++r) {
                int row = m0 + mi * 16 + quad * 4 + r;
                if (row < M) {
                    float v = acc[mi][ni][r] + bv;
                    if (dotanh) v = tanhf(v);
                    if (fin) ((float*)out)[(size_t)row * ldo + colc] = v;
                    else     ((unsigned short*)out)[(size_t)row * ldo + colc] = f2b(v);
                }
            }
        }
    }
}

static inline size_t al256(size_t x) { return (x + 255) & ~(size_t)255; }

extern "C" void kernel_launch(void* const* d_in, const int* in_sizes, int n_in,
                              void* d_out, int out_size, void* d_ws, size_t ws_size,
                              hipStream_t stream) {
    const void* x  = d_in[0];
    const int* src = (const int*)d_in[1];
    const int* dst = (const int*)d_in[2];
    const void* W1 = d_in[3]; const void* b1 = d_in[4];
    const void* W2 = d_in[5]; const void* b2 = d_in[6];
    const void* W3 = d_in[7]; const void* b3 = d_in[8];
    const int E = in_sizes[1];

    // workspace carve-up (~55.8 MB)
    char* p = (char*)d_ws;
    int* mode     = (int*)p;            p += 256;
    int* deg      = (int*)p;            p += al256((size_t)NN * 4);
    int* row_ptr  = (int*)p;            p += al256((size_t)(NN + 1) * 4);
    int* cursor   = (int*)p;            p += al256((size_t)NN * 4);
    float* dinv   = (float*)p;          p += al256((size_t)NN * 4);
    int* part     = (int*)p;            p += al256((size_t)64 * 4);
    int* csr      = (int*)p;            p += al256((size_t)E * 4);
    unsigned short* WT1 = (unsigned short*)p; p += al256((size_t)256 * 256 * 2);
    unsigned short* WT2 = (unsigned short*)p; p += al256((size_t)256 * 512 * 2);
    unsigned short* WT3 = (unsigned short*)p; p += al256((size_t)128 * 512 * 2);
    unsigned short* bb1 = (unsigned short*)p; p += al256((size_t)256 * 2);
    unsigned short* bb2 = (unsigned short*)p; p += al256((size_t)256 * 2);
    unsigned short* bb3 = (unsigned short*)p; p += al256((size_t)128 * 2);
    unsigned short* buf = (unsigned short*)p; p += al256((size_t)NN * 512 * 2);

    hipMemsetAsync(deg, 0, (size_t)NN * 4, stream);
    sniff_kernel<<<1, 64, 0, stream>>>((const unsigned short*)x, mode);

    int eb = (E + 255) / 256;
    const int SB = (NN + 1023) / 1024;     // 49 scan blocks
    deg_kernel<<<eb, 256, 0, stream>>>(dst, deg, E);
    part_kernel<<<SB, 256, 0, stream>>>(deg, part, NN);
    partscan_kernel<<<1, 64, 0, stream>>>(part, SB, row_ptr + NN);
    scan2_kernel<<<SB, 256, 0, stream>>>(deg, part, row_ptr, cursor, dinv, NN);
    fill_kernel<<<eb, 256, 0, stream>>>(src, dst, cursor, csr, E);

    transpose_kernel<<<(256 * 256 + 255) / 256, 256, 0, stream>>>(W1, WT1, 256, 256, mode);
    transpose_kernel<<<(512 * 256 + 255) / 256, 256, 0, stream>>>(W2, WT2, 512, 256, mode);
    transpose_kernel<<<(512 * 128 + 255) / 256, 256, 0, stream>>>(W3, WT3, 512, 128, mode);
    cvt_kernel<<<1, 256, 0, stream>>>(b1, bb1, 256, mode);
    cvt_kernel<<<1, 256, 0, stream>>>(b2, bb2, 256, mode);
    cvt_kernel<<<1, 256, 0, stream>>>(b3, bb3, 128, mode);
    pack_kernel<<<(NN * 16 + 255) / 256, 256, 0, stream>>>(x, buf, mode);

    const int SPMM_GRID = NN / 4;          // 4 waves (nodes) per 256-thread block
    const int GB = (NN + 63) / 64;         // gemm blocks (rows)

    // L1: buf = [x(0:128) | x1(128:256)]; gemm K=256 in-place -> cols 0:256
    spmm_kernel<2><<<SPMM_GRID, 256, 0, stream>>>(buf, 512, row_ptr, csr, dinv, buf + 128, 512);
    gemm_lds_kernel<8, 4><<<GB, 256, 0, stream>>>(buf, 512, WT1, bb1, buf, 512, NN, 1, 0, mode);
    // L2..L4: x1 into cols 256:512, gemm K=512 in-place -> cols 0:256
    spmm_kernel<4><<<SPMM_GRID, 256, 0, stream>>>(buf, 512, row_ptr, csr, dinv, buf + 256, 512);
    gemm_lds_kernel<16, 4><<<GB, 256, 0, stream>>>(buf, 512, WT2, bb2, buf, 512, NN, 1, 0, mode);
    spmm_kernel<4><<<SPMM_GRID, 256, 0, stream>>>(buf, 512, row_ptr, csr, dinv, buf + 256, 512);
    gemm_lds_kernel<16, 4><<<GB, 256, 0, stream>>>(buf, 512, WT2, bb2, buf, 512, NN, 1, 0, mode);
    spmm_kernel<4><<<SPMM_GRID, 256, 0, stream>>>(buf, 512, row_ptr, csr, dinv, buf + 256, 512);
    gemm_lds_kernel<16, 4><<<GB, 256, 0, stream>>>(buf, 512, WT2, bb2, buf, 512, NN, 1, 0, mode);
    // L5 (no tanh) -> d_out (50000 x 128, bf16 or fp32 per mode)
    spmm_kernel<4><<<SPMM_GRID, 256, 0, stream>>>(buf, 512, row_ptr, csr, dinv, buf + 256, 512);
    gemm_lds_kernel<16, 2><<<GB, 256, 0, stream>>>(buf, 512, WT3, bb3, d_out, 128, NN, 0, 1, mode);
}

// Round 5
// 620.793 us; speedup vs baseline: 1.9948x; 1.0272x over previous
//
#include <hip/hip_runtime.h>
#include <cmath>

#define NN 50000

typedef short v8s __attribute__((ext_vector_type(8)));   // 8 x bf16 (4 VGPRs)
typedef float v4f __attribute__((ext_vector_type(4)));

__device__ __forceinline__ float b2f(unsigned short u) {
    return __uint_as_float(((unsigned int)u) << 16);
}
__device__ __forceinline__ unsigned short f2b(float f) {
    unsigned int x = __float_as_uint(f);
    x += 0x7fffu + ((x >> 16) & 1u);          // round-to-nearest-even
    return (unsigned short)(x >> 16);
}

// async global->LDS, 16B per lane. LDS dest must be wave-contiguous (base + lane*16).
__device__ __forceinline__ void gld16(const void* g, void* l) {
    __builtin_amdgcn_global_load_lds(
        (const __attribute__((address_space(1))) unsigned int*)g,
        (__attribute__((address_space(3))) unsigned int*)l, 16, 0, 0);
}

// ---- dtype sniffer: mode=0 -> inputs are bf16, mode=1 -> inputs are float32 ----
__global__ void sniff_kernel(const unsigned short* __restrict__ x, int* __restrict__ mode) {
    if (threadIdx.x == 0 && blockIdx.x == 0) {
        int c = 0;
        for (int i = 0; i < 128; ++i) {
            unsigned int e = (x[i] >> 7) & 0xFFu;
            if (e >= 100u && e <= 140u) ++c;
        }
        *mode = (c >= 112) ? 0 : 1;
    }
}

// ---- degree histogram ----
__global__ void deg_kernel(const int* __restrict__ dst, int* __restrict__ deg, int E) {
    int e = blockIdx.x * blockDim.x + threadIdx.x;
    if (e < E) atomicAdd(&deg[dst[e]], 1);
}

// ---- hierarchical scan, stage 1: per-block (1024 elems) partial sums ----
__global__ void part_kernel(const int* __restrict__ deg, int* __restrict__ part, int n) {
    __shared__ int sm[256];
    int t = threadIdx.x;
    int base = blockIdx.x * 1024 + t * 4;
    int s = 0;
    if (base + 3 < n) {
        int4 v = *(const int4*)(deg + base);
        s = v.x + v.y + v.z + v.w;
    } else {
        for (int i = 0; i < 4; ++i) if (base + i < n) s += deg[base + i];
    }
    sm[t] = s;
    __syncthreads();
    for (int off = 128; off > 0; off >>= 1) {
        if (t < off) sm[t] += sm[t + off];
        __syncthreads();
    }
    if (t == 0) part[blockIdx.x] = sm[0];
}

// ---- stage 2: one wave exclusive-scans the partials (nb <= 64) ----
__global__ void partscan_kernel(int* __restrict__ part, int nb, int* __restrict__ total_out) {
    int t = threadIdx.x;
    int orig = (t < nb) ? part[t] : 0;
    int v = orig;
    for (int off = 1; off < 64; off <<= 1) {
        int u = __shfl_up(v, off, 64);
        if (t >= off) v += u;
    }
    if (t < nb) part[t] = v - orig;       // exclusive
    if (t == 63) *total_out = v;          // total = E
}

// ---- stage 3: block-local scan + offset; write row_ptr/cursor/dinv ----
__global__ void scan2_kernel(const int* __restrict__ deg, const int* __restrict__ part,
                             int* __restrict__ row_ptr, int* __restrict__ cursor,
                             float* __restrict__ dinv, int n) {
    __shared__ int sm[256];
    int t = threadIdx.x;
    int base = blockIdx.x * 1024 + t * 4;
    int d[4]; int s = 0;
#pragma unroll
    for (int i = 0; i < 4; ++i) { d[i] = (base + i < n) ? deg[base + i] : 0; s += d[i]; }
    sm[t] = s;
    __syncthreads();
    for (int off = 1; off < 256; off <<= 1) {
        int u = (t >= off) ? sm[t - off] : 0;
        __syncthreads();
        sm[t] += u;
        __syncthreads();
    }
    int run = part[blockIdx.x] + sm[t] - s;   // exclusive prefix at base
#pragma unroll
    for (int i = 0; i < 4; ++i) {
        int idx = base + i;
        if (idx < n) {
            row_ptr[idx] = run;
            cursor[idx]  = run;
            dinv[idx]    = (d[i] > 0) ? rsqrtf((float)d[i]) : 0.0f;
            run += d[i];
        }
    }
}

// ---- CSR fill (counting-sort placement) ----
__global__ void fill_kernel(const int* __restrict__ src, const int* __restrict__ dst,
                            int* __restrict__ cursor, int* __restrict__ csr, int E) {
    int e = blockIdx.x * blockDim.x + threadIdx.x;
    if (e < E) {
        int d = dst[e];
        int pos = atomicAdd(&cursor[d], 1);
        csr[pos] = src[e];
    }
}

// ---- W [K x F] (fp32 or bf16 per mode) -> WT [F x K] bf16 ----
__global__ void transpose_kernel(const void* __restrict__ W, unsigned short* __restrict__ WT,
                                 int K, int F, const int* __restrict__ modep) {
    int mode = *modep;
    int tid = blockIdx.x * blockDim.x + threadIdx.x;
    if (tid < K * F) {
        int n = tid / K, k = tid % K;
        unsigned short v = mode ? f2b(((const float*)W)[k * F + n])
                                : ((const unsigned short*)W)[k * F + n];
        WT[tid] = v;
    }
}

// ---- small convert (biases) ----
__global__ void cvt_kernel(const void* __restrict__ in, unsigned short* __restrict__ out,
                           int n, const int* __restrict__ modep) {
    int mode = *modep;
    int i = blockIdx.x * blockDim.x + threadIdx.x;
    if (i < n) out[i] = mode ? f2b(((const float*)in)[i]) : ((const unsigned short*)in)[i];
}

// ---- pack x (50000x128) into buf cols 0:128 (ld 512), 16B chunks ----
__global__ void pack_kernel(const void* __restrict__ x, unsigned short* __restrict__ buf,
                            const int* __restrict__ modep) {
    int mode = *modep;
    int tid = blockIdx.x * blockDim.x + threadIdx.x;
    if (tid < NN * 16) {                       // 16 chunks of 8 bf16 per row
        int n = tid >> 4, c = tid & 15;
        if (mode == 0) {
            ((uint4*)buf)[n * 64 + c] = ((const uint4*)x)[n * 16 + c];
        } else {
            const float* xf = (const float*)x + (size_t)n * 128 + c * 8;
            unsigned short o[8];
#pragma unroll
            for (int i = 0; i < 8; ++i) o[i] = f2b(xf[i]);
            *(uint4*)&buf[(size_t)n * 512 + c * 8] = *(const uint4*)o;
        }
    }
}

// ---- SpMM: one wave per dst node; x1[n] = -dinv[n] * sum_e dinv[src]*h[src]
// Wave cooperatively preloads up to 64 csr entries + dinv (one coalesced load +
// one gather per 64 edges), broadcasts via shfl, then issues 8 independent
// row-gathers per chunk -> no csr->dinv->row dependency chain in the hot loop.
template <int FPL>   // features per lane: F = 64*FPL (2 -> 128, 4 -> 256)
__global__ void spmm_kernel(const unsigned short* __restrict__ h, int ldh,
                            const int* __restrict__ row_ptr, const int* __restrict__ csr,
                            const float* __restrict__ dinv,
                            unsigned short* __restrict__ out, int ldo) {
    int node = blockIdx.x * 4 + (threadIdx.x >> 6);
    int lane = threadIdx.x & 63;
    int beg = row_ptr[node], end = row_ptr[node + 1];
    float acc[FPL];
#pragma unroll
    for (int i = 0; i < FPL; ++i) acc[i] = 0.f;
    const int col = lane * FPL;

    for (int base = beg; base < end; base += 64) {
        int cnt = min(64, end - base);
        int idx = base + lane;
        int sl = csr[(idx < end) ? idx : base];   // coalesced batch of edge indices
        float dl = dinv[sl];                       // one gather per 64 edges
        int g = 0;
        for (; g + 8 <= cnt; g += 8) {
            int s[8]; float d[8];
#pragma unroll
            for (int i = 0; i < 8; ++i) { s[i] = __shfl(sl, g + i); d[i] = __shfl(dl, g + i); }
            if (FPL == 4) {
                ushort4 v[8];
#pragma unroll
                for (int i = 0; i < 8; ++i)
                    v[i] = *(const ushort4*)(h + (size_t)s[i] * ldh + col);
#pragma unroll
                for (int i = 0; i < 8; ++i) {
                    acc[0] += d[i] * b2f(v[i].x); acc[1] += d[i] * b2f(v[i].y);
                    acc[2] += d[i] * b2f(v[i].z); acc[3] += d[i] * b2f(v[i].w);
                }
            } else {
                ushort2 v[8];
#pragma unroll
                for (int i = 0; i < 8; ++i)
                    v[i] = *(const ushort2*)(h + (size_t)s[i] * ldh + col);
#pragma unroll
                for (int i = 0; i < 8; ++i) {
                    acc[0] += d[i] * b2f(v[i].x); acc[1] += d[i] * b2f(v[i].y);
                }
            }
        }
        for (; g < cnt; ++g) {
            int sg = __shfl(sl, g);
            float dg = __shfl(dl, g);
            const unsigned short* hp = h + (size_t)sg * ldh + col;
            if (FPL == 4) {
                ushort4 v = *(const ushort4*)hp;
                acc[0] += dg * b2f(v.x); acc[1] += dg * b2f(v.y);
                acc[2] += dg * b2f(v.z); acc[3] += dg * b2f(v.w);
            } else {
                ushort2 v = *(const ushort2*)hp;
                acc[0] += dg * b2f(v.x); acc[1] += dg * b2f(v.y);
            }
        }
    }

    float dn = -dinv[node];
    unsigned short* op = out + (size_t)node * ldo + col;
    if (FPL == 4) {
        ushort4 o;
        o.x = f2b(acc[0] * dn); o.y = f2b(acc[1] * dn);
        o.z = f2b(acc[2] * dn); o.w = f2b(acc[3] * dn);
        *(ushort4*)op = o;
    } else {
        ushort2 o;
        o.x = f2b(acc[0] * dn); o.y = f2b(acc[1] * dn);
        *(ushort2*)op = o;
    }
}

// ---- LDS-staged MFMA GEMM (m97 structure) ----
// Block: 256 thr = 4 waves. Tile: 64(M) x NB(N), NB = 4*NTPW*16 (full output width).
// Wave w covers all 64 rows x cols [w*NTPW*16, +NTPW*16). K-loop BK=32, A/B tiles
// staged via global_load_lds(16B). In-place safe: block owns its rows, all A reads
// (K-loop) complete before epilogue stores.
template <int K32, int NTPW>
__global__ void gemm_lds_kernel(const unsigned short* __restrict__ A, int lda,
                                const unsigned short* __restrict__ WT,   // [NB x K] bf16
                                const unsigned short* __restrict__ bias, // bf16
                                void* __restrict__ out, int ldo,
                                int M, int dotanh, int is_final, const int* __restrict__ modep) {
    constexpr int K  = K32 * 32;
    constexpr int NB = 4 * NTPW * 16;
    constexpr int ACHUNK = 64 * 32 * 2 / 16;          // 256 16B-chunks
    constexpr int BCHUNK = NB * 32 * 2 / 16;
    constexpr int ROUNDS = (ACHUNK + BCHUNK) / 256;
    __shared__ unsigned short lds[(64 + NB) * 32];    // A[64][32] then B[NB][32]

    const int tid = threadIdx.x;
    const int wave = tid >> 6, lane = tid & 63, quad = lane >> 4, l16 = lane & 15;
    const int m0 = blockIdx.x * 64;

    v4f acc[4][NTPW];
#pragma unroll
    for (int mi = 0; mi < 4; ++mi)
#pragma unroll
        for (int ni = 0; ni < NTPW; ++ni) acc[mi][ni] = (v4f){0.f, 0.f, 0.f, 0.f};

    // precompute per-round global base pointers (k0-invariant part)
    const unsigned short* gp[ROUNDS];
#pragma unroll
    for (int r = 0; r < ROUNDS; ++r) {
        int c = tid + r * 256;
        if (c < ACHUNK) {
            int row = m0 + (c >> 2);
            if (row >= M) row = M - 1;
            gp[r] = A + (size_t)row * lda + (c & 3) * 8;
        } else {
            int cb = c - ACHUNK;
            gp[r] = WT + (size_t)(cb >> 2) * K + (cb & 3) * 8;
        }
    }

    const unsigned short* aT = lds;
    const unsigned short* bT = lds + 64 * 32;

    for (int k0 = 0; k0 < K; k0 += 32) {
#pragma unroll
        for (int r = 0; r < ROUNDS; ++r) {
            int c = tid + r * 256;
            gld16(gp[r] + k0, (void*)&lds[c * 8]);
        }
        __syncthreads();

        v8s a_frag[4], b_frag[NTPW];
#pragma unroll
        for (int mi = 0; mi < 4; ++mi)
            a_frag[mi] = *(const v8s*)&aT[(mi * 16 + l16) * 32 + quad * 8];
#pragma unroll
        for (int ni = 0; ni < NTPW; ++ni)
            b_frag[ni] = *(const v8s*)&bT[(wave * NTPW * 16 + ni * 16 + l16) * 32 + quad * 8];
#pragma unroll
        for (int mi = 0; mi < 4; ++mi)
#pragma unroll
            for (int ni = 0; ni < NTPW; ++ni)
                acc[mi][ni] = __builtin_amdgcn_mfma_f32_16x16x32_bf16(a_frag[mi], b_frag[ni],
                                                                      acc[mi][ni], 0, 0, 0);
        __syncthreads();
    }

    int fin = is_final ? *modep : 0;
#pragma unroll
    for (int ni = 0; ni < NTPW; ++ni) {
        int colc = wave * NTPW * 16 + ni * 16 + l16;
        float bv = b2f(bias[colc]);
#pragma unroll
        for (int mi = 0; mi < 4; ++mi) {
#pragma unroll
            for (int r = 0; r < 4; ++r) {
                int row = m0 + mi * 16 + quad * 4 + r;
                if (row < M) {
                    float v = acc[mi][ni][r] + bv;
                    if (dotanh) v = tanhf(v);
                    if (fin) ((float*)out)[(size_t)row * ldo + colc] = v;
                    else     ((unsigned short*)out)[(size_t)row * ldo + colc] = f2b(v);
                }
            }
        }
    }
}

static inline size_t al256(size_t x) { return (x + 255) & ~(size_t)255; }

extern "C" void kernel_launch(void* const* d_in, const int* in_sizes, int n_in,
                              void* d_out, int out_size, void* d_ws, size_t ws_size,
                              hipStream_t stream) {
    const void* x  = d_in[0];
    const int* src = (const int*)d_in[1];
    const int* dst = (const int*)d_in[2];
    const void* W1 = d_in[3]; const void* b1 = d_in[4];
    const void* W2 = d_in[5]; const void* b2 = d_in[6];
    const void* W3 = d_in[7]; const void* b3 = d_in[8];
    const int E = in_sizes[1];

    // workspace carve-up (~55.8 MB)
    char* p = (char*)d_ws;
    int* mode     = (int*)p;            p += 256;
    int* deg      = (int*)p;            p += al256((size_t)NN * 4);
    int* row_ptr  = (int*)p;            p += al256((size_t)(NN + 1) * 4);
    int* cursor   = (int*)p;            p += al256((size_t)NN * 4);
    float* dinv   = (float*)p;          p += al256((size_t)NN * 4);
    int* part     = (int*)p;            p += al256((size_t)64 * 4);
    int* csr      = (int*)p;            p += al256((size_t)E * 4);
    unsigned short* WT1 = (unsigned short*)p; p += al256((size_t)256 * 256 * 2);
    unsigned short* WT2 = (unsigned short*)p; p += al256((size_t)256 * 512 * 2);
    unsigned short* WT3 = (unsigned short*)p; p += al256((size_t)128 * 512 * 2);
    unsigned short* bb1 = (unsigned short*)p; p += al256((size_t)256 * 2);
    unsigned short* bb2 = (unsigned short*)p; p += al256((size_t)256 * 2);
    unsigned short* bb3 = (unsigned short*)p; p += al256((size_t)128 * 2);
    unsigned short* buf = (unsigned short*)p; p += al256((size_t)NN * 512 * 2);

    hipMemsetAsync(deg, 0, (size_t)NN * 4, stream);
    sniff_kernel<<<1, 64, 0, stream>>>((const unsigned short*)x, mode);

    int eb = (E + 255) / 256;
    const int SB = (NN + 1023) / 1024;     // 49 scan blocks
    deg_kernel<<<eb, 256, 0, stream>>>(dst, deg, E);
    part_kernel<<<SB, 256, 0, stream>>>(deg, part, NN);
    partscan_kernel<<<1, 64, 0, stream>>>(part, SB, row_ptr + NN);
    scan2_kernel<<<SB, 256, 0, stream>>>(deg, part, row_ptr, cursor, dinv, NN);
    fill_kernel<<<eb, 256, 0, stream>>>(src, dst, cursor, csr, E);

    transpose_kernel<<<(256 * 256 + 255) / 256, 256, 0, stream>>>(W1, WT1, 256, 256, mode);
    transpose_kernel<<<(512 * 256 + 255) / 256, 256, 0, stream>>>(W2, WT2, 512, 256, mode);
    transpose_kernel<<<(512 * 128 + 255) / 256, 256, 0, stream>>>(W3, WT3, 512, 128, mode);
    cvt_kernel<<<1, 256, 0, stream>>>(b1, bb1, 256, mode);
    cvt_kernel<<<1, 256, 0, stream>>>(b2, bb2, 256, mode);
    cvt_kernel<<<1, 256, 0, stream>>>(b3, bb3, 128, mode);
    pack_kernel<<<(NN * 16 + 255) / 256, 256, 0, stream>>>(x, buf, mode);

    const int SPMM_GRID = NN / 4;          // 4 waves (nodes) per 256-thread block
    const int GB = (NN + 63) / 64;         // gemm blocks (rows)

    // L1: buf = [x(0:128) | x1(128:256)]; gemm K=256 in-place -> cols 0:256
    spmm_kernel<2><<<SPMM_GRID, 256, 0, stream>>>(buf, 512, row_ptr, csr, dinv, buf + 128, 512);
    gemm_lds_kernel<8, 4><<<GB, 256, 0, stream>>>(buf, 512, WT1, bb1, buf, 512, NN, 1, 0, mode);
    // L2..L4: x1 into cols 256:512, gemm K=512 in-place -> cols 0:256
    spmm_kernel<4><<<SPMM_GRID, 256, 0, stream>>>(buf, 512, row_ptr, csr, dinv, buf + 256, 512);
    gemm_lds_kernel<16, 4><<<GB, 256, 0, stream>>>(buf, 512, WT2, bb2, buf, 512, NN, 1, 0, mode);
    spmm_kernel<4><<<SPMM_GRID, 256, 0, stream>>>(buf, 512, row_ptr, csr, dinv, buf + 256, 512);
    gemm_lds_kernel<16, 4><<<GB, 256, 0, stream>>>(buf, 512, WT2, bb2, buf, 512, NN, 1, 0, mode);
    spmm_kernel<4><<<SPMM_GRID, 256, 0, stream>>>(buf, 512, row_ptr, csr, dinv, buf + 256, 512);
    gemm_lds_kernel<16, 4><<<GB, 256, 0, stream>>>(buf, 512, WT2, bb2, buf, 512, NN, 1, 0, mode);
    // L5 (no tanh) -> d_out (50000 x 128, bf16 or fp32 per mode)
    spmm_kernel<4><<<SPMM_GRID, 256, 0, stream>>>(buf, 512, row_ptr, csr, dinv, buf + 256, 512);
    gemm_lds_kernel<16, 2><<<GB, 256, 0, stream>>>(buf, 512, WT3, bb3, d_out, 128, NN, 0, 1, mode);
}